// Round 2
// baseline (1081.606 us; speedup 1.0000x reference)
//
#include <hip/hip_runtime.h>

#define NQ    10000
#define CD    256
#define KNBR  16
#define NCAND 32
#define NTILE 157   // ceil(10048/64)

typedef short bs8 __attribute__((ext_vector_type(8)));
typedef float f32x4 __attribute__((ext_vector_type(4)));
typedef unsigned short u16;
typedef unsigned int u32;
typedef unsigned short us4 __attribute__((ext_vector_type(4)));

__device__ __forceinline__ float bf2f(u16 u){
  union { u32 i; float f; } c; c.i = ((u32)u) << 16; return c.f;
}
__device__ __forceinline__ u16 f2bf(float f){
  union { float f; u32 i; } c; c.f = f;
  u32 u = c.i;
  u += 0x7fffu + ((u >> 16) & 1u);   // RTNE
  return (u16)(u >> 16);
}
template<int DT>
__device__ __forceinline__ float ldf(const void* p, int i){
  if (DT) return bf2f(((const u16*)p)[i]);
  return ((const float*)p)[i];
}
__device__ __forceinline__ void ldpair(const u16* p, float& a, float& b){
  u32 v = *(const u32*)p;
  a = bf2f((u16)(v & 0xffffu));
  b = bf2f((u16)(v >> 16));
}

// ---------------- dtype detect: flag=0 f32, flag=1 bf16 ------------------
// Low u16 of each u32 word of x: as bf16 its exponent clusters near 127 if
// inputs are bf16 pairs; if inputs are f32 it's uniform mantissa bits.
__global__ __launch_bounds__(256) void detect_kernel(const u32* __restrict__ xw, int* __restrict__ flag)
{
  __shared__ int cnt;
  if (threadIdx.x == 0) cnt = 0;
  __syncthreads();
  const u32 w = xw[threadIdx.x];
  const int e = (int)((w >> 7) & 0xff);          // exponent of low-half-as-bf16
  if (e >= 120 && e <= 131) atomicAdd(&cnt, 1);
  __syncthreads();
  if (threadIdx.x == 0) flag[0] = (cnt >= 128) ? 1 : 0;
}

// ---------------- x -> bf16 copy/convert ---------------------------------
template<int DT>
__global__ __launch_bounds__(256) void cvt_kernel(const void* __restrict__ xin, u16* __restrict__ xh,
                                                  const int* __restrict__ flag)
{
  if (flag[0] != DT) return;
  const int idx = (blockIdx.x * 256 + threadIdx.x) * 4;
  us4 r;
  if (DT == 0){
    const float4 v = *(const float4*)((const float*)xin + idx);
    r[0] = f2bf(v.x); r[1] = f2bf(v.y); r[2] = f2bf(v.z); r[3] = f2bf(v.w);
  } else {
    r = *(const us4*)((const u16*)xin + idx);
  }
  *(us4*)(xh + idx) = r;
}

// ---------------- prep: transpose weight halves to bf16 ------------------
// wt roles: 0 AqS=Wq[0:256] 1 AkS=Wk[0:256] 2 B1S=W1[256:512]
//           3 BqD=Wq[256:512] 4 BkD=Wk[256:512] 5 A1D=W1[0:256]
template<int DT>
__global__ __launch_bounds__(256) void prep_kernel(const void* __restrict__ Wq, const void* __restrict__ Wk,
                                                   const void* __restrict__ W1, const void* __restrict__ W2,
                                                   u16* __restrict__ wt, u16* __restrict__ w2t,
                                                   const int* __restrict__ flag)
{
  if (flag[0] != DT) return;
  const int job = blockIdx.x, n = threadIdx.x;
  const void* src; int soff; u16* dst;
  switch (job){
    case 0: src = Wq; soff = 0;     dst = wt;          break;
    case 1: src = Wk; soff = 0;     dst = wt + 65536;  break;
    case 2: src = W1; soff = 65536; dst = wt + 131072; break;
    case 3: src = Wq; soff = 65536; dst = wt + 196608; break;
    case 4: src = Wk; soff = 65536; dst = wt + 262144; break;
    case 5: src = W1; soff = 0;     dst = wt + 327680; break;
    default: src = W2; soff = 0;    dst = w2t;         break;
  }
  for (int c = 0; c < 256; ++c)
    dst[n*256 + c] = f2bf(ldf<DT>(src, soff + c*256 + n));
}

// ---------------- row squared norms (native precision -> f32) ------------
template<int DT>
__global__ __launch_bounds__(256) void n2_kernel(const void* __restrict__ x, float* __restrict__ n2,
                                                 const int* __restrict__ flag)
{
  if (flag[0] != DT) return;
  const int tid = threadIdx.x, wave = tid >> 6, lane = tid & 63;
  const int row = blockIdx.x * 4 + wave;
  const int base = row * CD + lane * 4;
  float s;
  if (DT == 0){
    const float4 v = *(const float4*)((const float*)x + base);
    s = v.x*v.x + v.y*v.y + v.z*v.z + v.w*v.w;
  } else {
    const u32* p = (const u32*)x + (base >> 1);
    const u32 w0 = p[0], w1 = p[1];
    const float a = bf2f((u16)(w0 & 0xffff)), b = bf2f((u16)(w0 >> 16));
    const float c = bf2f((u16)(w1 & 0xffff)), d = bf2f((u16)(w1 >> 16));
    s = a*a + b*b + c*c + d*d;
  }
  #pragma unroll
  for (int m = 1; m < 64; m <<= 1) s += __shfl_xor(s, m);
  if (lane == 0) n2[row] = s;
}

// ---------------- projections: P = X @ Whalf (6 roles) -------------------
__global__ __launch_bounds__(256) void pgemm_kernel(const u16* __restrict__ xh,
                                                    const u16* __restrict__ wt,
                                                    u16* __restrict__ SP, u16* __restrict__ DP)
{
  const int tid = threadIdx.x, wave = tid >> 6, lane = tid & 63;
  const int l15 = lane & 15, lq = lane >> 4;
  const int row0 = blockIdx.x * 16;
  const int cg0 = blockIdx.y * 64 + wave * 16;
  const int p = cg0 >> 8;
  const int ncol = (cg0 & 255) + l15;

  const u16* ap = xh + (row0 + l15) * CD + lq * 8;
  const u16* bp = wt + p * 65536 + ncol * CD + lq * 8;
  f32x4 acc = {0.f, 0.f, 0.f, 0.f};
  #pragma unroll
  for (int ks = 0; ks < 8; ++ks)
    acc = __builtin_amdgcn_mfma_f32_16x16x32_bf16(*(const bs8*)(ap + ks*32),
                                                  *(const bs8*)(bp + ks*32), acc, 0, 0, 0);
  #pragma unroll
  for (int q = 0; q < 4; ++q){
    const int node = row0 + 4*lq + q;
    const u16 v = f2bf(acc[q]);
    if (p < 3) SP[node*768 + p*256 + ncol] = v;
    else       DP[node*768 + (p-3)*256 + ncol] = v;
  }
}

// ---------------- Gram (bf16) + top-32 candidate selection ---------------
__global__ __launch_bounds__(256) void knn_cand_kernel(const u16* __restrict__ xh,
                                                       const float* __restrict__ n2,
                                                       int* __restrict__ cand)
{
  __shared__ float sc[4][16][17];
  __shared__ float mg_d[16][16][16];
  __shared__ int   mg_i[16][16][16];

  const int tid = threadIdx.x;
  const int wave = tid >> 6, lane = tid & 63;
  const int row0 = blockIdx.x * 16;
  const int l15 = lane & 15, lq = lane >> 4;

  bs8 a[8];
  const u16* ap = xh + (row0 + l15) * CD + lq * 8;
  #pragma unroll
  for (int ks = 0; ks < 8; ++ks) a[ks] = *(const bs8*)(ap + ks * 32);

  const float nrow = n2[row0 + l15];
  const int myrow = row0 + l15;

  float ld[16]; int li[16];
  #pragma unroll
  for (int s = 0; s < 16; ++s){ ld[s] = __builtin_inff(); li[s] = -1; }

  for (int t = 0; t < NTILE; ++t){
    const int colbase = t * 64 + wave * 16;
    int bcol = colbase + l15; if (bcol > NQ-1) bcol = NQ-1;
    const u16* bp = xh + bcol * CD + lq * 8;
    f32x4 acc = {0.f, 0.f, 0.f, 0.f};
    #pragma unroll
    for (int ks = 0; ks < 8; ++ks)
      acc = __builtin_amdgcn_mfma_f32_16x16x32_bf16(a[ks], *(const bs8*)(bp + ks*32), acc, 0, 0, 0);
    #pragma unroll
    for (int q = 0; q < 4; ++q) sc[wave][4*lq + q][l15] = acc[q];
    __syncthreads();
    #pragma unroll
    for (int u = 0; u < 4; ++u){
      const int c = colbase + 4*lq + u;
      const float g = sc[wave][l15][4*lq + u];
      int cc = c; if (cc > NQ-1) cc = NQ-1;
      const float nc = n2[cc];
      float dd = nrow + nc - 2.f * g;
      const bool ok = (c < NQ) && (c != myrow);
      dd = ok ? dd : __builtin_inff();
      if (dd <= ld[15]){
        float cdv = dd; int civ = c;
        #pragma unroll
        for (int s = 0; s < 16; ++s){
          const bool cmp = cdv <= ld[s];
          const float tdv = ld[s]; const int tiv = li[s];
          ld[s] = cmp ? cdv : tdv; li[s] = cmp ? civ : tiv;
          cdv = cmp ? tdv : cdv;  civ = cmp ? tiv : civ;
        }
      }
    }
    __syncthreads();
  }

  const int lid = wave * 4 + lq;
  #pragma unroll
  for (int s = 0; s < 16; ++s){
    mg_d[l15][lid][s] = ld[s];
    mg_i[l15][lid][s] = li[s];
  }
  __syncthreads();

  if (tid < 64){
    const int r = tid >> 2, sub = tid & 3;
    int p0=0,p1=0,p2=0,p3=0;
    float h0 = mg_d[r][sub*4+0][0], h1 = mg_d[r][sub*4+1][0],
          h2 = mg_d[r][sub*4+2][0], h3 = mg_d[r][sub*4+3][0];
    int   i0 = mg_i[r][sub*4+0][0], i1 = mg_i[r][sub*4+1][0],
          i2 = mg_i[r][sub*4+2][0], i3 = mg_i[r][sub*4+3][0];
    for (int it = 0; it < NCAND; ++it){
      float dl = h0; int il = i0;
      if (h1 < dl || (h1 == dl && i1 < il)){ dl = h1; il = i1; }
      if (h2 < dl || (h2 == dl && i2 < il)){ dl = h2; il = i2; }
      if (h3 < dl || (h3 == dl && i3 < il)){ dl = h3; il = i3; }
      float od; int oi;
      od = __shfl_xor(dl, 1); oi = __shfl_xor(il, 1);
      if (od < dl || (od == dl && oi < il)){ dl = od; il = oi; }
      od = __shfl_xor(dl, 2); oi = __shfl_xor(il, 2);
      if (od < dl || (od == dl && oi < il)){ dl = od; il = oi; }
      if (sub == 0) cand[(row0 + r) * NCAND + it] = il;
      if      (i0 == il){ ++p0; h0 = (p0<16)? mg_d[r][sub*4+0][p0] : __builtin_inff(); i0 = (p0<16)? mg_i[r][sub*4+0][p0] : -1; }
      else if (i1 == il){ ++p1; h1 = (p1<16)? mg_d[r][sub*4+1][p1] : __builtin_inff(); i1 = (p1<16)? mg_i[r][sub*4+1][p1] : -1; }
      else if (i2 == il){ ++p2; h2 = (p2<16)? mg_d[r][sub*4+2][p2] : __builtin_inff(); i2 = (p2<16)? mg_i[r][sub*4+2][p2] : -1; }
      else if (i3 == il){ ++p3; h3 = (p3<16)? mg_d[r][sub*4+3][p3] : __builtin_inff(); i3 = (p3<16)? mg_i[r][sub*4+3][p3] : -1; }
    }
  }
}

// ---------------- exact rescore of 32 candidates -> top-16 ---------------
template<int DT>
__global__ __launch_bounds__(256) void rescore_kernel(const void* __restrict__ x, const float* __restrict__ n2,
                                                      const int* __restrict__ cand, int* __restrict__ knn,
                                                      const int* __restrict__ flag)
{
  if (flag[0] != DT) return;
  const int tid = threadIdx.x, wave = tid >> 6, lane = tid & 63;
  const int i = blockIdx.x * 4 + wave;
  const int base = i * CD + lane * 4;
  float xi0, xi1, xi2, xi3;
  if (DT == 0){
    const float4 v = *(const float4*)((const float*)x + base);
    xi0 = v.x; xi1 = v.y; xi2 = v.z; xi3 = v.w;
  } else {
    const u32* p = (const u32*)x + (base >> 1);
    const u32 w0 = p[0], w1 = p[1];
    xi0 = bf2f((u16)(w0 & 0xffff)); xi1 = bf2f((u16)(w0 >> 16));
    xi2 = bf2f((u16)(w1 & 0xffff)); xi3 = bf2f((u16)(w1 >> 16));
  }
  const float n2i = n2[i];
  const int cown = lane & 31;
  float myd = 0.f; int myi = -1;
  for (int c = 0; c < NCAND; ++c){
    const int j = cand[i * NCAND + c];
    const int jb = j * CD + lane * 4;
    float a0, a1, a2, a3;
    if (DT == 0){
      const float4 v = *(const float4*)((const float*)x + jb);
      a0 = v.x; a1 = v.y; a2 = v.z; a3 = v.w;
    } else {
      const u32* p = (const u32*)x + (jb >> 1);
      const u32 w0 = p[0], w1 = p[1];
      a0 = bf2f((u16)(w0 & 0xffff)); a1 = bf2f((u16)(w0 >> 16));
      a2 = bf2f((u16)(w1 & 0xffff)); a3 = bf2f((u16)(w1 >> 16));
    }
    float pdt = xi0*a0 + xi1*a1 + xi2*a2 + xi3*a3;
    #pragma unroll
    for (int m = 1; m < 64; m <<= 1) pdt += __shfl_xor(pdt, m);
    const float d = n2i + n2[j] - 2.f * pdt;
    if (c == cown){ myd = d; myi = j; }
  }
  int rank = 0;
  #pragma unroll
  for (int m = 1; m < NCAND; ++m){
    int oc = cown + m; if (oc >= NCAND) oc -= NCAND;
    const float od = __shfl(myd, oc);
    const int   oi = __shfl(myi, oc);
    rank += (od < myd || (od == myd && oi < myi)) ? 1 : 0;
  }
  if (lane < NCAND && rank < KNBR) knn[i * KNBR + rank] = myi;
}

// ---------------- fused edge + aggregate + lin2 --------------------------
template<int DT>
__global__ __launch_bounds__(256) void edge_kernel(
    const void* __restrict__ x, const u16* __restrict__ SP, const u16* __restrict__ DP,
    const int* __restrict__ knn, const u16* __restrict__ w2t,
    const void* __restrict__ bq, const void* __restrict__ bk,
    const void* __restrict__ b1, const void* __restrict__ b2,
    void* __restrict__ out, const int* __restrict__ flag)
{
  if (flag[0] != DT) return;
  __shared__ float4 Tl[4][256];
  const int tid = threadIdx.x, wave = tid >> 6, lane = tid & 63;
  const int i = blockIdx.x * 4 + wave;
  const int c0 = 2 * lane, c2 = 128 + 2 * lane;

  const u16* dp = DP + i * 768;
  float Bq0,Bq1,Bq2,Bq3, Bk0,Bk1,Bk2,Bk3, A10,A11,A12,A13;
  ldpair(dp + c0,       Bq0, Bq1); ldpair(dp + c2,       Bq2, Bq3);
  ldpair(dp + 256 + c0, Bk0, Bk1); ldpair(dp + 256 + c2, Bk2, Bk3);
  ldpair(dp + 512 + c0, A10, A11); ldpair(dp + 512 + c2, A12, A13);
  const float xi0 = ldf<DT>(x, i*CD + c0),   xi1 = ldf<DT>(x, i*CD + c0 + 1);
  const float xi2 = ldf<DT>(x, i*CD + c2),   xi3 = ldf<DT>(x, i*CD + c2 + 1);
  Bq0 += ldf<DT>(bq, c0); Bq1 += ldf<DT>(bq, c0+1); Bq2 += ldf<DT>(bq, c2); Bq3 += ldf<DT>(bq, c2+1);
  Bk0 += ldf<DT>(bk, c0); Bk1 += ldf<DT>(bk, c0+1); Bk2 += ldf<DT>(bk, c2); Bk3 += ldf<DT>(bk, c2+1);
  A10 += ldf<DT>(b1, c0); A11 += ldf<DT>(b1, c0+1); A12 += ldf<DT>(b1, c2); A13 += ldf<DT>(b1, c2+1);

  float S00=0,S01=0,S10=0,S11=0;
  float Ta[4][4] = {{0,0,0,0},{0,0,0,0},{0,0,0,0},{0,0,0,0}};

  for (int e = 0; e < KNBR; ++e){
    const int j = knn[i * KNBR + e];
    const u16* sp = SP + j * 768;
    float Aq0,Aq1,Aq2,Aq3, Ak0,Ak1,Ak2,Ak3, B10,B11,B12,B13;
    ldpair(sp + c0,       Aq0, Aq1); ldpair(sp + c2,       Aq2, Aq3);
    ldpair(sp + 256 + c0, Ak0, Ak1); ldpair(sp + 256 + c2, Ak2, Ak3);
    ldpair(sp + 512 + c0, B10, B11); ldpair(sp + 512 + c2, B12, B13);
    const float Q0=Aq0+Bq0, Q1=Aq1+Bq1, Q2=Aq2+Bq2, Q3=Aq3+Bq3;
    const float K0=Ak0+Bk0, K1=Ak1+Bk1, K2=Ak2+Bk2, K3=Ak3+Bk3;
    float e00 = Q0*K0 + Q1*K1;
    float e11 = Q2*K2 + Q3*K3;
    float e01 = Q0*K2 + Q1*K3;
    float e10 = Q2*K0 + Q3*K1;
    #pragma unroll
    for (int m = 1; m < 64; m <<= 1){
      e00 += __shfl_xor(e00, m);
      e01 += __shfl_xor(e01, m);
      e10 += __shfl_xor(e10, m);
      e11 += __shfl_xor(e11, m);
    }
    e00 *= 0.0625f; e01 *= 0.0625f; e10 *= 0.0625f; e11 *= 0.0625f;
    const float h0 = fmaxf(A10 + B10, 0.f) + xi0;
    const float h1 = fmaxf(A11 + B11, 0.f) + xi1;
    const float h2 = fmaxf(A12 + B12, 0.f) + xi2;
    const float h3 = fmaxf(A13 + B13, 0.f) + xi3;
    S00 += e00; S01 += e01; S10 += e10; S11 += e11;
    Ta[0][0]+=h0*e00; Ta[0][1]+=h0*e01; Ta[0][2]+=h0*e10; Ta[0][3]+=h0*e11;
    Ta[1][0]+=h1*e00; Ta[1][1]+=h1*e01; Ta[1][2]+=h1*e10; Ta[1][3]+=h1*e11;
    Ta[2][0]+=h2*e00; Ta[2][1]+=h2*e01; Ta[2][2]+=h2*e10; Ta[2][3]+=h2*e11;
    Ta[3][0]+=h3*e00; Ta[3][1]+=h3*e01; Ta[3][2]+=h3*e10; Ta[3][3]+=h3*e11;
  }
  Tl[wave][c0  ] = make_float4(Ta[0][0],Ta[0][1],Ta[0][2],Ta[0][3]);
  Tl[wave][c0+1] = make_float4(Ta[1][0],Ta[1][1],Ta[1][2],Ta[1][3]);
  Tl[wave][c2  ] = make_float4(Ta[2][0],Ta[2][1],Ta[2][2],Ta[2][3]);
  Tl[wave][c2+1] = make_float4(Ta[3][0],Ta[3][1],Ta[3][2],Ta[3][3]);
  __syncthreads();

  const u16* w0 = w2t + (4*lane+0)*CD;
  const u16* w1 = w2t + (4*lane+1)*CD;
  const u16* w2 = w2t + (4*lane+2)*CD;
  const u16* w3 = w2t + (4*lane+3)*CD;
  float o0=0.f,o1=0.f,o2=0.f,o3=0.f;
  for (int cb = 0; cb < CD; cb += 8){
    const bs8 va = *(const bs8*)(w0 + cb);
    const bs8 vb = *(const bs8*)(w1 + cb);
    const bs8 vc = *(const bs8*)(w2 + cb);
    const bs8 vd = *(const bs8*)(w3 + cb);
    #pragma unroll
    for (int kk = 0; kk < 8; ++kk){
      const float4 tv = Tl[wave][cb + kk];
      const float wa = bf2f((u16)va[kk]);
      const float wb = bf2f((u16)vb[kk]);
      const float wc = bf2f((u16)vc[kk]);
      const float wd = bf2f((u16)vd[kk]);
      o0 += wa*tv.x + wb*tv.z;
      o1 += wa*tv.y + wb*tv.w;
      o2 += wc*tv.x + wd*tv.z;
      o3 += wc*tv.y + wd*tv.w;
    }
  }
  const float b2a = ldf<DT>(b2, 4*lane),     b2b = ldf<DT>(b2, 4*lane+1);
  const float b2c = ldf<DT>(b2, 4*lane+2),   b2d = ldf<DT>(b2, 4*lane+3);
  o0 += b2a*S00 + b2b*S10;
  o1 += b2a*S01 + b2b*S11;
  o2 += b2c*S00 + b2d*S10;
  o3 += b2c*S01 + b2d*S11;
  const float sc16 = 0.0625f;
  if (DT == 0){
    *(float4*)((float*)out + i*CD + 4*lane) =
        make_float4(o0*sc16, o1*sc16, o2*sc16, o3*sc16);
  } else {
    us4 r;
    r[0]=f2bf(o0*sc16); r[1]=f2bf(o1*sc16); r[2]=f2bf(o2*sc16); r[3]=f2bf(o3*sc16);
    *(us4*)((u16*)out + i*CD + 4*lane) = r;
  }
}

extern "C" void kernel_launch(void* const* d_in, const int* in_sizes, int n_in,
                              void* d_out, int out_size, void* d_ws, size_t ws_size,
                              hipStream_t stream)
{
  const void* x  = d_in[0];
  const void* W1 = d_in[1];
  const void* b1 = d_in[2];
  const void* W2 = d_in[3];
  const void* b2 = d_in[4];
  const void* Wq = d_in[5];
  const void* bq = d_in[6];
  const void* Wk = d_in[7];
  const void* bk = d_in[8];

  char* ws = (char*)d_ws;
  int*   flag = (int*)ws;                    // 64 B
  u16*   xh   = (u16*)(ws + 64);             // 10000x256 bf16   5,120,000
  u16*   wt   = (u16*)(ws + 5120064);        // 6x256x256 bf16     786,432
  u16*   w2t  = (u16*)(ws + 5906496);        // 256x256 bf16       131,072
  float* n2   = (float*)(ws + 6037568);      // 10000 f32           40,000
  int*   cand = (int*)(ws + 6077568);        // 10000x32 int     1,280,000
  int*   knn  = (int*)(ws + 7357568);        // 10000x16 int       640,000
  u16*   SP   = (u16*)(ws + 7997568);        // 10000x768 bf16  15,360,000
  u16*   DP   = (u16*)(ws + 23357568);       // 10000x768 bf16  15,360,000
  // total 38,717,568 bytes

  detect_kernel<<<1, 256, 0, stream>>>((const u32*)x, flag);

  cvt_kernel<0><<<2500, 256, 0, stream>>>(x, xh, flag);
  cvt_kernel<1><<<2500, 256, 0, stream>>>(x, xh, flag);
  prep_kernel<0><<<7, 256, 0, stream>>>(Wq, Wk, W1, W2, wt, w2t, flag);
  prep_kernel<1><<<7, 256, 0, stream>>>(Wq, Wk, W1, W2, wt, w2t, flag);
  n2_kernel<0><<<2500, 256, 0, stream>>>(x, n2, flag);
  n2_kernel<1><<<2500, 256, 0, stream>>>(x, n2, flag);

  pgemm_kernel<<<dim3(625, 24), 256, 0, stream>>>(xh, wt, SP, DP);
  knn_cand_kernel<<<625, 256, 0, stream>>>(xh, n2, cand);

  rescore_kernel<0><<<2500, 256, 0, stream>>>(x, n2, cand, knn, flag);
  rescore_kernel<1><<<2500, 256, 0, stream>>>(x, n2, cand, knn, flag);

  edge_kernel<0><<<2500, 256, 0, stream>>>(x, SP, DP, knn, w2t, bq, bk, b1, b2, d_out, flag);
  edge_kernel<1><<<2500, 256, 0, stream>>>(x, SP, DP, knn, w2t, bq, bk, b1, b2, d_out, flag);
}